// Round 5
// baseline (100.988 us; speedup 1.0000x reference)
//
#include <hip/hip_runtime.h>
#include <stdint.h>

typedef short bf16x8 __attribute__((ext_vector_type(8)));
typedef float f32x4 __attribute__((ext_vector_type(4)));

#define NROWS 8192
#define DIM   128
// sqrt(10/ln2): dot of scaled z gives 10*cos/ln2, so exp2(dot)=exp(10*cos)
#define ZSCALE 3.7982824f
#define LN2F  0.6931471805599453f

__device__ __forceinline__ unsigned short f32_to_bf16_bits(float x) {
  union { float f; uint32_t u; } v; v.f = x;
  uint32_t r = v.u + 0x7FFFu + ((v.u >> 16) & 1u);  // RNE
  return (unsigned short)(r >> 16);
}

// K0: one-time W transpose to bf16 (Wt[n][k] = W[k][n]) + zero accumulators.
__global__ __launch_bounds__(256) void k_wprep(const float* __restrict__ W,
                                               unsigned short* __restrict__ Wt,
                                               float* __restrict__ sumexp,
                                               float* __restrict__ topacc) {
  const int idx = blockIdx.x * 256 + threadIdx.x;  // 0..16383
  const int n = idx >> 7, k = idx & 127;
  Wt[idx] = f32_to_bf16_bits(W[k * DIM + n]);
  if (idx < NROWS) sumexp[idx] = 0.f;
  if (idx == 0) topacc[0] = 0.f;
}

// K1: z = bf16( ZSCALE * normalize(anchor @ W + bias) )
// 128 blocks x 4 waves; wave owns 16 output rows, all 128 cols.
__global__ __launch_bounds__(256) void k_proj_norm(
    const float* __restrict__ anchor, const unsigned short* __restrict__ Wt,
    const float* __restrict__ bias, unsigned short* __restrict__ z) {
  const int t = threadIdx.x;
  const int wv = t >> 6, l = t & 63, g = l >> 4, q = l & 15;
  const int rowbase = blockIdx.x * 64 + wv * 16;

  f32x4 acc[8];
#pragma unroll
  for (int tj = 0; tj < 8; ++tj) acc[tj] = (f32x4){0.f, 0.f, 0.f, 0.f};

#pragma unroll
  for (int ks = 0; ks < 4; ++ks) {
    const float* ap = anchor + (size_t)(rowbase + q) * DIM + ks * 32 + g * 8;
    const f32x4 a0 = *(const f32x4*)ap, a1 = *(const f32x4*)(ap + 4);
    bf16x8 a;
#pragma unroll
    for (int e = 0; e < 4; ++e) {
      a[e] = (short)f32_to_bf16_bits(a0[e]);
      a[4 + e] = (short)f32_to_bf16_bits(a1[e]);
    }
#pragma unroll
    for (int tj = 0; tj < 8; ++tj) {
      const bf16x8 b =
          *(const bf16x8*)(Wt + (size_t)(tj * 16 + q) * DIM + ks * 32 + g * 8);
      acc[tj] = __builtin_amdgcn_mfma_f32_16x16x32_bf16(a, b, acc[tj], 0, 0, 0);
    }
  }

  // C/D layout: col = q, row = 4*g + r
  float sumsq[4] = {0.f, 0.f, 0.f, 0.f};
#pragma unroll
  for (int tj = 0; tj < 8; ++tj) {
    float bv = bias[tj * 16 + q];
#pragma unroll
    for (int r = 0; r < 4; ++r) {
      acc[tj][r] += bv;
      sumsq[r] += acc[tj][r] * acc[tj][r];
    }
  }
#pragma unroll
  for (int r = 0; r < 4; ++r) {
#pragma unroll
    for (int m = 1; m < 16; m <<= 1) sumsq[r] += __shfl_xor(sumsq[r], m, 64);
  }
  float inv[4];
#pragma unroll
  for (int r = 0; r < 4; ++r) inv[r] = ZSCALE / fmaxf(sqrtf(sumsq[r]), 1e-12f);

#pragma unroll
  for (int tj = 0; tj < 8; ++tj)
#pragma unroll
    for (int r = 0; r < 4; ++r)
      z[(size_t)(rowbase + 4 * g + r) * DIM + tj * 16 + q] =
          f32_to_bf16_bits(acc[tj][r] * inv[r]);
}

// K2: fused Z @ Z^T -> exp2 -> row sums. No LDS/barriers; z (2 MB) is
// L2-resident. Wave = 32 i-rows (A stays in 32 VGPRs), streams 256 j-cols
// in 16-col steps with an explicit 2-deep register pipeline on B (named
// buffers, fully unrolled -> static indexing). Grid = 64 igrp x 32 jbi =
// 2048 blocks = 8192 waves -> 4 waves/SIMD resident (TLP hides L2 latency).
__global__ __launch_bounds__(256) void k_simloss(
    const unsigned short* __restrict__ z, float* __restrict__ sumexp,
    float* __restrict__ topacc) {
  const int t = threadIdx.x;
  const int wv = t >> 6, l = t & 63, g = l >> 4, q = l & 15;
  const int igrp = (int)blockIdx.x >> 5, jbi = (int)blockIdx.x & 31;
  const int r0 = igrp * 128 + wv * 32;  // wave's 32 i-rows
  const int cb = jbi * 256;             // block's 256 j-cols
  const int posr = (r0 + 4096) & 8191;  // 32-aligned start of positive cols

  // A frags: afr[ti][ks] -> row r0+ti*16+q, k = ks*32+g*8..+8  (32 VGPR)
  bf16x8 afr[2][4];
#pragma unroll
  for (int ti = 0; ti < 2; ++ti)
#pragma unroll
    for (int ks = 0; ks < 4; ++ks)
      afr[ti][ks] = *(const bf16x8*)(z + (size_t)(r0 + ti * 16 + q) * DIM +
                                     ks * 32 + g * 8);

  float sums[2][4] = {{0.f, 0.f, 0.f, 0.f}, {0.f, 0.f, 0.f, 0.f}};
  float topv = 0.f;

  auto LOADB = [&](bf16x8 b[4], int c0) {
#pragma unroll
    for (int ks = 0; ks < 4; ++ks)
      b[ks] = *(const bf16x8*)(z + (size_t)(c0 + q) * DIM + ks * 32 + g * 8);
  };
  auto COMPUTE = [&](const bf16x8 b[4], int c0) {
    f32x4 acc[2];
    acc[0] = (f32x4){0.f, 0.f, 0.f, 0.f};
    acc[1] = acc[0];
#pragma unroll
    for (int ti = 0; ti < 2; ++ti)
#pragma unroll
      for (int ks = 0; ks < 4; ++ks)
        acc[ti] = __builtin_amdgcn_mfma_f32_16x16x32_bf16(afr[ti][ks], b[ks],
                                                          acc[ti], 0, 0, 0);
    const bool dg = (c0 & ~31) == r0;    // 16-col tile hits diagonal
    const bool ps = (c0 & ~31) == posr;  // 16-col tile hits positive pairs
    if (dg | ps) {
#pragma unroll
      for (int ti = 0; ti < 2; ++ti)
#pragma unroll
        for (int r = 0; r < 4; ++r) {
          const float d = acc[ti][r];
          const int row_g = r0 + ti * 16 + 4 * g + r;
          const int col_g = c0 + q;
          float e = __builtin_amdgcn_exp2f(d);
          if (dg && col_g == row_g) e = 0.f;                      // j == i
          if (ps && col_g == ((row_g + 4096) & 8191)) topv += d;  // pos pair
          sums[ti][r] += e;
        }
    } else {
#pragma unroll
      for (int ti = 0; ti < 2; ++ti)
#pragma unroll
        for (int r = 0; r < 4; ++r)
          sums[ti][r] += __builtin_amdgcn_exp2f(acc[ti][r]);
    }
  };

  // 2-deep register pipeline over 16 steps of 16 cols (static names, full unroll)
  bf16x8 bA[4], bB[4];
  LOADB(bA, cb);
#pragma unroll
  for (int p = 0; p < 8; ++p) {
    LOADB(bB, cb + p * 32 + 16);
    COMPUTE(bA, cb + p * 32);
    if (p < 7) LOADB(bA, cb + p * 32 + 32);
    COMPUTE(bB, cb + p * 32 + 16);
  }

  // reduce partial row-sums across the 16 q-lanes (row id depends on g only)
#pragma unroll
  for (int ti = 0; ti < 2; ++ti)
#pragma unroll
    for (int r = 0; r < 4; ++r) {
#pragma unroll
      for (int m = 1; m < 16; m <<= 1)
        sums[ti][r] += __shfl_xor(sums[ti][r], m, 64);
    }
  if (q == 0) {
#pragma unroll
    for (int ti = 0; ti < 2; ++ti)
#pragma unroll
      for (int r = 0; r < 4; ++r)
        atomicAdd(&sumexp[r0 + ti * 16 + 4 * g + r], sums[ti][r]);
  }

  // top-term: only waves whose j-range contains their rows' positive columns
  if ((posr & ~255) == cb) {
#pragma unroll
    for (int m = 1; m < 64; m <<= 1) topv += __shfl_xor(topv, m, 64);
    if (l == 0) atomicAdd(topacc, topv);
  }
}

// K3: loss = (sum_i ln(bottom_i) - ln2 * sum_top) / (b-1)
__global__ __launch_bounds__(256) void k_final(const float* __restrict__ sumexp,
                                               const float* __restrict__ topacc,
                                               float* __restrict__ out) {
  __shared__ float red[4];
  const int t = threadIdx.x;
  float s = 0.f;
  for (int r = t; r < NROWS; r += 256) s += logf(sumexp[r]);
#pragma unroll
  for (int m = 1; m < 64; m <<= 1) s += __shfl_xor(s, m, 64);
  if ((t & 63) == 0) red[t >> 6] = s;
  __syncthreads();
  if (t == 0) {
    const float S1 = red[0] + red[1] + red[2] + red[3];
    out[0] = (S1 - LN2F * topacc[0]) * (1.0f / (float)(NROWS - 1));
  }
}

extern "C" void kernel_launch(void* const* d_in, const int* in_sizes, int n_in,
                              void* d_out, int out_size, void* d_ws, size_t ws_size,
                              hipStream_t stream) {
  const float* anchor = (const float*)d_in[0];
  const float* W = (const float*)d_in[1];
  const float* bias = (const float*)d_in[2];
  float* out = (float*)d_out;

  char* ws = (char*)d_ws;
  unsigned short* z = (unsigned short*)ws;                         // 2 MB bf16 [8192][128]
  float* sumexp = (float*)(ws + (size_t)2 * 1024 * 1024);          // 32 KB
  float* topacc = (float*)(ws + (size_t)2 * 1024 * 1024 + 32768);  // 4 B
  unsigned short* Wt = (unsigned short*)(ws + (size_t)2 * 1024 * 1024 + 36864); // 32 KB

  k_wprep<<<dim3(64), dim3(256), 0, stream>>>(W, Wt, sumexp, topacc);
  k_proj_norm<<<dim3(NROWS / 64), dim3(256), 0, stream>>>(anchor, Wt, bias, z);
  k_simloss<<<dim3(64 * 32), dim3(256), 0, stream>>>(z, sumexp, topacc);
  k_final<<<dim3(1), dim3(256), 0, stream>>>(sumexp, topacc, out);
}

// Round 6
// 51.127 us; speedup vs baseline: 1.9752x; 1.9752x over previous
//
#include <hip/hip_runtime.h>
#include <stdint.h>

typedef short bf16x8 __attribute__((ext_vector_type(8)));
typedef float f32x4 __attribute__((ext_vector_type(4)));

#define NROWS 8192
#define DIM   128
// sqrt(10/ln2): dot of scaled z gives 10*cos/ln2, so exp2(dot)=exp(10*cos)
#define ZSCALE 3.7982824f
#define LN2F  0.6931471805599453f

// zf layout (fragment-linear): chunk (b, ks) = 1KB at (b*4+ks)*1024 bytes;
// lane l (g=l>>4, q=l&15) holds z[b*16+q][ks*32+g*8 .. +8] as bf16x8.
// => every MFMA A/B fragment load is base + l*16 (single coalesced transaction).

__device__ __forceinline__ unsigned short f32_to_bf16_bits(float x) {
  union { float f; uint32_t u; } v; v.f = x;
  uint32_t r = v.u + 0x7FFFu + ((v.u >> 16) & 1u);  // RNE
  return (unsigned short)(r >> 16);
}

// K0: Wtf = W in B-fragment order (chunk (tj,ks): lane l holds
// W[ks*32+g*8 .. +8][tj*16+q]); also zero sumexp/topacc.
__global__ __launch_bounds__(256) void k_wprep(const float* __restrict__ W,
                                               unsigned short* __restrict__ Wtf,
                                               float* __restrict__ sumexp,
                                               float* __restrict__ topacc) {
  const int idx = blockIdx.x * 256 + threadIdx.x;  // grid 64 -> 16384
  if (idx < 2048) {
    const int l = idx & 63, chunk = idx >> 6;      // chunk = tj*4+ks
    const int tj = chunk >> 2, ks = chunk & 3, g = l >> 4, q = l & 15;
    const float* wp = W + (size_t)(ks * 32 + g * 8) * DIM + tj * 16 + q;
    bf16x8 o;
#pragma unroll
    for (int e = 0; e < 8; ++e) o[e] = (short)f32_to_bf16_bits(wp[(size_t)e * DIM]);
    *(bf16x8*)(Wtf + (size_t)idx * 8) = o;
  }
  if (idx < NROWS) sumexp[idx] = 0.f;
  if (idx == 0) topacc[0] = 0.f;
}

// K1: zf = fragment-order bf16( ZSCALE * normalize(anchor @ W + bias) ).
// 512 blocks (2/CU) x 16 rows; 4 waves k-split (wave wv computes the K=32
// slice ks=wv), LDS reduce, then normalize + direct fragment-order store.
__global__ __launch_bounds__(256) void k_proj_norm(
    const float* __restrict__ anchor, const unsigned short* __restrict__ Wtf,
    const float* __restrict__ bias, unsigned short* __restrict__ zf) {
  __shared__ float part[4][16][132];  // padded cols: +4 to break bank patterns
  const int t = threadIdx.x;
  const int wv = t >> 6, l = t & 63, g = l >> 4, q = l & 15;
  const int rb = blockIdx.x * 16;

  // A frag (K-slice wv): anchor[rb+q][wv*32+g*8 .. +8]
  const float* ap = anchor + (size_t)(rb + q) * DIM + wv * 32 + g * 8;
  const f32x4 a0 = *(const f32x4*)ap, a1 = *(const f32x4*)(ap + 4);
  bf16x8 a;
#pragma unroll
  for (int e = 0; e < 4; ++e) {
    a[e] = (short)f32_to_bf16_bits(a0[e]);
    a[4 + e] = (short)f32_to_bf16_bits(a1[e]);
  }

  f32x4 acc[8];
#pragma unroll
  for (int tj = 0; tj < 8; ++tj) acc[tj] = (f32x4){0.f, 0.f, 0.f, 0.f};
#pragma unroll
  for (int tj = 0; tj < 8; ++tj) {
    const bf16x8 b = *(const bf16x8*)(Wtf + (size_t)((tj * 4 + wv) * 64 + l) * 8);
    acc[tj] = __builtin_amdgcn_mfma_f32_16x16x32_bf16(a, b, acc[tj], 0, 0, 0);
  }

  // partials: C layout col=q,row=4g+r -> part[wv][4g+r][tj*16+q]
#pragma unroll
  for (int tj = 0; tj < 8; ++tj)
#pragma unroll
    for (int r = 0; r < 4; ++r) part[wv][4 * g + r][tj * 16 + q] = acc[tj][r];
  __syncthreads();

  // reduce k-slices + bias + normalize + fragment-order store
  const int row = t >> 4, c = t & 15;  // c = 8-col chunk
  float v[8];
#pragma unroll
  for (int e = 0; e < 8; ++e) v[e] = bias[c * 8 + e];
#pragma unroll
  for (int s = 0; s < 4; ++s) {
    const f32x4 p0 = *(const f32x4*)&part[s][row][c * 8];
    const f32x4 p1 = *(const f32x4*)&part[s][row][c * 8 + 4];
#pragma unroll
    for (int e = 0; e < 4; ++e) {
      v[e] += p0[e];
      v[4 + e] += p1[e];
    }
  }
  float ss = 0.f;
#pragma unroll
  for (int e = 0; e < 8; ++e) ss += v[e] * v[e];
#pragma unroll
  for (int m = 1; m < 16; m <<= 1) ss += __shfl_xor(ss, m, 64);
  const float inv = ZSCALE / fmaxf(sqrtf(ss), 1e-12f);

  bf16x8 o;
#pragma unroll
  for (int e = 0; e < 8; ++e) o[e] = (short)f32_to_bf16_bits(v[e] * inv);
  const int ks = c >> 2, gg = c & 3;  // k-chunk coords of cols c*8..+8
  *(bf16x8*)(zf + (size_t)(((blockIdx.x * 4 + ks) * 64) + gg * 16 + row) * 8) = o;
}

// K2: fused Z @ Z^T -> exp2 -> row sums. No LDS; all fragment loads are
// lane-linear (base + l*16) from zf -> single-transaction coalesced.
// Wave = 64 i-rows; block = 4 waves x 256 i-rows, 256 j-cols.
// Grid = 32 x 32 = 1024 blocks; 2-deep register pipeline on B.
__global__ __launch_bounds__(256) void k_simloss(
    const unsigned short* __restrict__ zf, float* __restrict__ sumexp,
    float* __restrict__ topacc) {
  const int t = threadIdx.x;
  const int wv = t >> 6, l = t & 63, g = l >> 4, q = l & 15;
  const int igrp = (int)blockIdx.x >> 5, jbi = (int)blockIdx.x & 31;
  const int r0 = igrp * 256 + wv * 64;  // wave's 64 i-rows
  const int cb = jbi * 256;             // block's 256 j-cols
  const int posr = (r0 + 4096) & 8191;  // 64-aligned start of positive cols

  // A frags: afr[ti][ks] for rows r0+ti*16+q -> zf chunk ((r0>>4)+ti, ks)
  bf16x8 afr[4][4];
#pragma unroll
  for (int ti = 0; ti < 4; ++ti)
#pragma unroll
    for (int ks = 0; ks < 4; ++ks)
      afr[ti][ks] = *(const bf16x8*)(
          zf + (size_t)((((r0 >> 4) + ti) * 4 + ks) * 512 + l * 8));

  float sums[4][4];
#pragma unroll
  for (int ti = 0; ti < 4; ++ti)
#pragma unroll
    for (int r = 0; r < 4; ++r) sums[ti][r] = 0.f;
  float topv = 0.f;

  // lane-diagonal predicate: C elem (ti,r) has row r0+ti*16+4g+r, col c0+q;
  // within a diagonal-hitting 16x16 tile equality is q == 4g+r.
  bool qeq[4];
#pragma unroll
  for (int r = 0; r < 4; ++r) qeq[r] = (q == 4 * g + r);

  auto LOADB = [&](bf16x8 b[4], int c0) {
    const int bcol = c0 >> 4;
#pragma unroll
    for (int ks = 0; ks < 4; ++ks)
      b[ks] = *(const bf16x8*)(zf + (size_t)((bcol * 4 + ks) * 512 + l * 8));
  };
  auto COMPUTE = [&](const bf16x8 b[4], int c0) {
    f32x4 acc[4];
#pragma unroll
    for (int ti = 0; ti < 4; ++ti) acc[ti] = (f32x4){0.f, 0.f, 0.f, 0.f};
#pragma unroll
    for (int ti = 0; ti < 4; ++ti)
#pragma unroll
      for (int ks = 0; ks < 4; ++ks)
        acc[ti] = __builtin_amdgcn_mfma_f32_16x16x32_bf16(afr[ti][ks], b[ks],
                                                          acc[ti], 0, 0, 0);
    // which ti-tile (if any) hits diagonal / positive pairs at this c0
    const int dgo = c0 - r0, pso = c0 - posr;
    const int dgti = ((unsigned)dgo < 64u) ? (dgo >> 4) : -1;
    const int psti = ((unsigned)pso < 64u) ? (pso >> 4) : -1;
#pragma unroll
    for (int ti = 0; ti < 4; ++ti) {
#pragma unroll
      for (int r = 0; r < 4; ++r) {
        const float d = acc[ti][r];
        float e = __builtin_amdgcn_exp2f(d);
        if (ti == dgti && qeq[r]) e = 0.f;       // j == i
        if (ti == psti && qeq[r]) topv += d;     // j == (i+4096)%8192
        sums[ti][r] += e;
      }
    }
  };

  // 16 j-steps of 16 cols, 2-deep register pipeline (static names)
  bf16x8 bA[4], bB[4];
  LOADB(bA, cb);
#pragma unroll
  for (int p = 0; p < 8; ++p) {
    LOADB(bB, cb + p * 32 + 16);
    COMPUTE(bA, cb + p * 32);
    if (p < 7) LOADB(bA, cb + p * 32 + 32);
    COMPUTE(bB, cb + p * 32 + 16);
  }

  // reduce row-sums across the 16 q-lanes
#pragma unroll
  for (int ti = 0; ti < 4; ++ti)
#pragma unroll
    for (int r = 0; r < 4; ++r) {
#pragma unroll
      for (int m = 1; m < 16; m <<= 1)
        sums[ti][r] += __shfl_xor(sums[ti][r], m, 64);
    }
  if (q == 0) {
#pragma unroll
    for (int ti = 0; ti < 4; ++ti)
#pragma unroll
      for (int r = 0; r < 4; ++r)
        atomicAdd(&sumexp[r0 + ti * 16 + 4 * g + r], sums[ti][r]);
  }

  // top-term: only the block whose j-range contains this wave's positive cols
  if ((posr & ~255) == cb) {
#pragma unroll
    for (int m = 1; m < 64; m <<= 1) topv += __shfl_xor(topv, m, 64);
    if (l == 0) atomicAdd(topacc, topv);
  }
}

// K3: loss = (sum_i ln(bottom_i) - ln2 * sum_top) / (b-1)
__global__ __launch_bounds__(256) void k_final(const float* __restrict__ sumexp,
                                               const float* __restrict__ topacc,
                                               float* __restrict__ out) {
  __shared__ float red[4];
  const int t = threadIdx.x;
  float s = 0.f;
  for (int r = t; r < NROWS; r += 256) s += logf(sumexp[r]);
#pragma unroll
  for (int m = 1; m < 64; m <<= 1) s += __shfl_xor(s, m, 64);
  if ((t & 63) == 0) red[t >> 6] = s;
  __syncthreads();
  if (t == 0) {
    const float S1 = red[0] + red[1] + red[2] + red[3];
    out[0] = (S1 - LN2F * topacc[0]) * (1.0f / (float)(NROWS - 1));
  }
}

extern "C" void kernel_launch(void* const* d_in, const int* in_sizes, int n_in,
                              void* d_out, int out_size, void* d_ws, size_t ws_size,
                              hipStream_t stream) {
  const float* anchor = (const float*)d_in[0];
  const float* W = (const float*)d_in[1];
  const float* bias = (const float*)d_in[2];
  float* out = (float*)d_out;

  char* ws = (char*)d_ws;
  unsigned short* zf = (unsigned short*)ws;                        // 2 MB fragment-order z
  float* sumexp = (float*)(ws + (size_t)2 * 1024 * 1024);          // 32 KB
  float* topacc = (float*)(ws + (size_t)2 * 1024 * 1024 + 32768);  // 4 B
  unsigned short* Wtf = (unsigned short*)(ws + (size_t)2 * 1024 * 1024 + 36864); // 32 KB

  k_wprep<<<dim3(64), dim3(256), 0, stream>>>(W, Wtf, sumexp, topacc);
  k_proj_norm<<<dim3(NROWS / 16), dim3(256), 0, stream>>>(anchor, Wtf, bias, zf);
  k_simloss<<<dim3(32 * 32), dim3(256), 0, stream>>>(zf, sumexp, topacc);
  k_final<<<dim3(1), dim3(256), 0, stream>>>(sumexp, topacc, out);
}